// Round 3
// baseline (362.619 us; speedup 1.0000x reference)
//
#include <hip/hip_runtime.h>
#include <math.h>

typedef unsigned short ushort_t;
typedef unsigned int uint_t;
typedef __attribute__((ext_vector_type(8))) short short8;
typedef __attribute__((ext_vector_type(4))) float f32x4;
typedef __attribute__((ext_vector_type(4))) uint_t uint4v;
typedef __attribute__((ext_vector_type(2))) uint_t uint2v;

#define NSEQ 16384
#define SCALE_Q 0.17677669529663687f   // 32^-0.5
#define RMS_K 11.313708498984761f      // sqrt(128)

__device__ __forceinline__ ushort_t f2bf(float f) {
  uint_t u = __builtin_bit_cast(uint_t, f);
  u += 0x7FFFu + ((u >> 16) & 1u);
  return (ushort_t)(u >> 16);
}
__device__ __forceinline__ uint_t f2bf2(float lo, float hi) {
  return (uint_t)f2bf(lo) | ((uint_t)f2bf(hi) << 16);
}
__device__ __forceinline__ float bf2f(ushort_t u) {
  return __builtin_bit_cast(float, ((uint_t)u) << 16);
}
// swizzles: slot-XOR (bank spread) + word-pair-XOR on row bit4.
// A: [rows][128] bf16 buffers (256B rows);  B: [rows][64] bf16 buffers (128B rows)
__device__ __forceinline__ int swzA(int row, int col) {
  int slot = (col >> 3) ^ (row & 7);
  int w2 = ((col >> 1) & 3) ^ (((row >> 4) & 1) << 1);
  return row * 128 + slot * 8 + w2 * 2 + (col & 1);
}
__device__ __forceinline__ int swzB(int row, int col) {
  int slot = ((col >> 3) & 7) ^ (row & 7);
  int w2 = ((col >> 1) & 3) ^ (((row >> 4) & 1) << 1);
  return row * 64 + slot * 8 + w2 * 2 + (col & 1);
}
__device__ __forceinline__ short8 ldfragA(const ushort_t* lds, int row, int col8, int pp) {
  int slot = (col8 >> 3) ^ (row & 7);
  const uint4v q = *(const uint4v*)&lds[row * 128 + slot * 8];
  uint4v r;
  if (pp) { r.x = q.z; r.y = q.w; r.z = q.x; r.w = q.y; } else { r = q; }
  return __builtin_bit_cast(short8, r);
}
__device__ __forceinline__ short8 ldfragB(const ushort_t* lds, int row, int col8, int pp) {
  int slot = ((col8 >> 3) & 7) ^ (row & 7);
  const uint4v q = *(const uint4v*)&lds[row * 64 + slot * 8];
  uint4v r;
  if (pp) { r.x = q.z; r.y = q.w; r.z = q.x; r.w = q.y; } else { r = q; }
  return __builtin_bit_cast(short8, r);
}
#define MFMA(a, b, c) __builtin_amdgcn_mfma_f32_16x16x32_bf16((a), (b), (c), 0, 0, 0)

// ---------------------------------------------------------------------------
// kP: pack weights to bf16 in MFMA B-fragment order (unchanged from round 2).
// ---------------------------------------------------------------------------
__global__ void kP(const float* __restrict__ w_qkv, const float* __restrict__ w_out,
                   ushort_t* __restrict__ wkv_pk, ushort_t* __restrict__ wq_pk,
                   ushort_t* __restrict__ wout_pk) {
  const int i = blockIdx.x * 256 + threadIdx.x;
  const int j = i & 7, lane = (i >> 3) & 63;
  const int l15 = lane & 15, l4 = lane >> 4;
  if (i < 32768) {                       // w_kv^T
    const int rest = i >> 9, Nt = rest & 15, kk = rest >> 4;
    wkv_pk[i] = f2bf(w_qkv[(128 + Nt * 16 + l15) * 128 + kk * 32 + l4 * 8 + j]);
  } else if (i < 49152) {                // w_q^T
    const int i2 = i - 32768, rest = i2 >> 9, Nt = rest & 7, kk = rest >> 3;
    wq_pk[i2] = f2bf(w_qkv[(Nt * 16 + l15) * 128 + kk * 32 + l4 * 8 + j]);
  } else if (i < 65536) {                // w_out^T
    const int i2 = i - 49152, rest = i2 >> 9, Nt = rest & 7, kk = rest >> 3;
    wout_pk[i2] = f2bf(w_out[(Nt * 16 + l15) * 128 + kk * 32 + l4 * 8 + j]);
  }
}

// ---------------------------------------------------------------------------
// kA: per (b, 256-n chunk), 64-n subtiles. LDS 49.7KB -> 2 blocks/CU.
// ---------------------------------------------------------------------------
__global__ __launch_bounds__(512, 4)
void kA(const float* __restrict__ x, const ushort_t* __restrict__ wkv_pk,
        float* __restrict__ ctx_acc, float* __restrict__ S_glob) {
  __shared__ ushort_t xs[64 * 128];    // 16KB  x bf16 [n 64][c 128]
  __shared__ ushort_t eks[128 * 64];   // 16KB  exp(k) [d 128][n 64]
  __shared__ ushort_t vs[128 * 64];    // 16KB  v      [e 128][n 64]
  __shared__ float S_lds[128];
  const int b = blockIdx.y, blk = blockIdx.x;
  const int tid = threadIdx.x, wave = tid >> 6, lane = tid & 63;
  const int mg = wave >> 2, ng = wave & 3;   // proj: n-group(32), kvrow-group(64)
  const int h = wave >> 1, dt = wave & 1;    // ctx: head, d-tile
  const int l15 = lane & 15, l4 = lane >> 4;
  if (tid < 128) S_lds[tid] = 0.f;

  short8 wf[4][4];
#pragma unroll
  for (int kk = 0; kk < 4; ++kk)
#pragma unroll
    for (int nt = 0; nt < 4; ++nt)
      wf[kk][nt] = *(const short8*)&wkv_pk[((kk * 16 + ng * 4 + nt) * 64 + lane) * 8];

  const f32x4 fzero = {0.f, 0.f, 0.f, 0.f};
  f32x4 cacc[2]; cacc[0] = fzero; cacc[1] = fzero;
  float sacc[4] = {0.f, 0.f, 0.f, 0.f};

  const int sn = tid & 63, cb = (tid >> 6) * 16;
  const float* xb = x + (size_t)b * 128 * NSEQ + blk * 256 + sn;
  float pf[16];
#pragma unroll
  for (int i = 0; i < 16; ++i) pf[i] = xb[(size_t)(cb + i) * NSEQ];

  for (int s = 0; s < 4; ++s) {
    __syncthreads();
    {
      uint_t* xw = (uint_t*)xs;
#pragma unroll
      for (int i = 0; i < 16; i += 2)
        xw[swzA(sn, cb + i) >> 1] = f2bf2(pf[i], pf[i + 1]);
    }
    if (s < 3) {
#pragma unroll
      for (int i = 0; i < 16; ++i) pf[i] = xb[(size_t)(cb + i) * NSEQ + (s + 1) * 64];
    }
    __syncthreads();
    // ---- projection: 64n x 256kv, K=128
    f32x4 pacc[2][4];
#pragma unroll
    for (int mt = 0; mt < 2; ++mt)
#pragma unroll
      for (int nt = 0; nt < 4; ++nt) pacc[mt][nt] = fzero;
#pragma unroll
    for (int kk = 0; kk < 4; ++kk) {
      short8 af[2];
#pragma unroll
      for (int mt = 0; mt < 2; ++mt)
        af[mt] = ldfragA(xs, mg * 32 + mt * 16 + l15, kk * 32 + l4 * 8, mt & 1);
#pragma unroll
      for (int mt = 0; mt < 2; ++mt)
#pragma unroll
        for (int nt = 0; nt < 4; ++nt)
          pacc[mt][nt] = MFMA(af[mt], wf[kk][nt], pacc[mt][nt]);
    }
    // ---- epilogue: exp(k)->eks, v->vs
#pragma unroll
    for (int nt = 0; nt < 4; ++nt) {
      const int kvr = ng * 64 + nt * 16 + l15;
#pragma unroll
      for (int mt = 0; mt < 2; ++mt) {
        const int nq = mg * 32 + mt * 16 + l4 * 4;
        f32x4 v = pacc[mt][nt];
        if (ng < 2) {
          float e0 = __expf(v.x), e1 = __expf(v.y), e2 = __expf(v.z), e3 = __expf(v.w);
          sacc[nt] += (e0 + e1) + (e2 + e3);
          uint_t* ew = (uint_t*)eks;
          ew[swzB(kvr, nq) >> 1] = f2bf2(e0, e1);
          ew[swzB(kvr, nq + 2) >> 1] = f2bf2(e2, e3);
        } else {
          uint_t* vw = (uint_t*)vs;
          vw[swzB(kvr - 128, nq) >> 1] = f2bf2(v.x, v.y);
          vw[swzB(kvr - 128, nq + 2) >> 1] = f2bf2(v.z, v.w);
        }
      }
    }
    __syncthreads();
    // ---- ctx MFMA over 64 n (2 K-steps)
    const int drow = h * 32 + dt * 16 + l15;
#pragma unroll
    for (int kk2 = 0; kk2 < 2; ++kk2) {
      short8 ea = ldfragB(eks, drow, kk2 * 32 + l4 * 8, dt);
#pragma unroll
      for (int et = 0; et < 2; ++et) {
        short8 vb = ldfragB(vs, h * 32 + et * 16 + l15, kk2 * 32 + l4 * 8, et);
        cacc[et] = MFMA(ea, vb, cacc[et]);
      }
    }
  }
#pragma unroll
  for (int et = 0; et < 2; ++et) {
    float* dst = &ctx_acc[((((b * 4 + h) * 2 + dt) * 2 + et) * 64 + lane) * 4];
    atomicAdd(dst + 0, cacc[et].x);
    atomicAdd(dst + 1, cacc[et].y);
    atomicAdd(dst + 2, cacc[et].z);
    atomicAdd(dst + 3, cacc[et].w);
  }
  if (ng < 2) {
#pragma unroll
    for (int nt = 0; nt < 4; ++nt)
      atomicAdd(&S_lds[ng * 64 + nt * 16 + l15], sacc[nt]);
  }
  __syncthreads();
  if (tid < 128) atomicAdd(&S_glob[b * 128 + tid], S_lds[tid]);
}

// ---------------------------------------------------------------------------
// kB: ctx = ctx_acc / S, packed to bf16 B-fragment order (unchanged).
// ---------------------------------------------------------------------------
__global__ void kB(const float* __restrict__ ctx_acc, const float* __restrict__ S_glob,
                   ushort_t* __restrict__ ctx_pk) {
  const int bh = blockIdx.x;
  const int b = bh >> 2, hh = bh & 3;
  const int t = threadIdx.x;
  const int lane = t & 63, dtet = t >> 6, dt = dtet >> 1, et = dtet & 1;
  const int l15 = lane & 15, q = lane >> 4;
  const f32x4 c4 = *(const f32x4*)&ctx_acc[(((bh * 2 + dt) * 2 + et) * 64 + lane) * 4];
  const int dbase = dt * 16 + q * 4;
  ushort_t o[4];
#pragma unroll
  for (int r = 0; r < 4; ++r) {
    const float S = S_glob[b * 128 + hh * 32 + dbase + r];
    o[r] = f2bf(c4[r] / S);
  }
  const int lp = l15 + (((dbase >> 3) & 3) << 4);
  uint2v w;
  w.x = (uint_t)o[0] | ((uint_t)o[1] << 16);
  w.y = (uint_t)o[2] | ((uint_t)o[3] << 16);
  *(uint2v*)&ctx_pk[((bh * 2 + et) * 64 + lp) * 8 + (q & 1) * 4] = w;
}

// ---------------------------------------------------------------------------
// kC: q proj -> softmax(d) -> out_att -> w_out GEMM -> RMSNorm -> store.
// 64-n subtiles, LDS 49.3KB -> 2 blocks/CU.
// ---------------------------------------------------------------------------
__global__ __launch_bounds__(512, 4)
void kC(const float* __restrict__ x, const ushort_t* __restrict__ wq_pk,
        const ushort_t* __restrict__ wout_pk, const ushort_t* __restrict__ ctx_pk,
        const float* __restrict__ b_out, const float* __restrict__ g,
        float* __restrict__ out) {
  __shared__ ushort_t xs[64 * 128];    // x bf16 [n 64][c 128]; reused for qhat [n][qrow]
  __shared__ ushort_t qlog[128 * 64];  // q logits [qrow 128][n 64]
  __shared__ ushort_t yT[64 * 128];    // y bf16 [n 64][hid 128]
  __shared__ float nrm[64];
  __shared__ float bias_l[128], g_l[128];
  const int b = blockIdx.y, blk = blockIdx.x;
  const int tid = threadIdx.x, wave = tid >> 6, lane = tid & 63;
  const int mg = wave >> 1, ng = wave & 1;   // n-group(16), col-group(64)
  const int l15 = lane & 15, l4 = lane >> 4;
  if (tid < 128) { bias_l[tid] = b_out[tid]; g_l[tid] = g[tid]; }

  short8 cfr[4];
#pragma unroll
  for (int nt = 0; nt < 4; ++nt) {
    const int Nt = ng * 4 + nt, hh = Nt >> 1, et = Nt & 1;
    cfr[nt] = *(const short8*)&ctx_pk[(((b * 4 + hh) * 2 + et) * 64 + lane) * 8];
  }
  const f32x4 fzero = {0.f, 0.f, 0.f, 0.f};
  const int sn = tid & 63, cb = (tid >> 6) * 16;
  const float* xb = x + (size_t)b * 128 * NSEQ + blk * 256 + sn;
  float pf[16];
#pragma unroll
  for (int i = 0; i < 16; ++i) pf[i] = __builtin_nontemporal_load(&xb[(size_t)(cb + i) * NSEQ]);

  for (int s = 0; s < 4; ++s) {
    __syncthreads();
    if (tid < 64) nrm[tid] = 0.f;
    {
      uint_t* xw = (uint_t*)xs;
#pragma unroll
      for (int i = 0; i < 16; i += 2)
        xw[swzA(sn, cb + i) >> 1] = f2bf2(pf[i], pf[i + 1]);
    }
    if (s < 3) {
#pragma unroll
      for (int i = 0; i < 16; ++i)
        pf[i] = __builtin_nontemporal_load(&xb[(size_t)(cb + i) * NSEQ + (s + 1) * 64]);
    }
    __syncthreads();
    // ---- Q projection: 64n x 128qrow, K=128
    f32x4 pacc[4];
#pragma unroll
    for (int nt = 0; nt < 4; ++nt) pacc[nt] = fzero;
#pragma unroll
    for (int kk = 0; kk < 4; ++kk) {
      short8 wqf[4];
#pragma unroll
      for (int nt = 0; nt < 4; ++nt)
        wqf[nt] = *(const short8*)&wq_pk[((kk * 8 + ng * 4 + nt) * 64 + lane) * 8];
      short8 af = ldfragA(xs, mg * 16 + l15, kk * 32 + l4 * 8, mg & 1);
#pragma unroll
      for (int nt = 0; nt < 4; ++nt)
        pacc[nt] = MFMA(af, wqf[nt], pacc[nt]);
    }
    {
      uint_t* qw = (uint_t*)qlog;
#pragma unroll
      for (int nt = 0; nt < 4; ++nt) {
        const int qrow = ng * 64 + nt * 16 + l15;
        const int nq = mg * 16 + l4 * 4;
        qw[swzB(qrow, nq) >> 1] = f2bf2(pacc[nt].x, pacc[nt].y);
        qw[swzB(qrow, nq + 2) >> 1] = f2bf2(pacc[nt].z, pacc[nt].w);
      }
    }
    __syncthreads();
    // ---- softmax over d (threads 0..255: one (head, n) each)
    if (tid < 256) {
      const int n2 = tid & 63, hq = tid >> 6;
      float lv[32];
#pragma unroll
      for (int i = 0; i < 32; ++i) lv[i] = bf2f(qlog[swzB(hq * 32 + i, n2)]);
      float m = lv[0];
#pragma unroll
      for (int i = 1; i < 32; ++i) m = fmaxf(m, lv[i]);
      float ssum = 0.f;
#pragma unroll
      for (int i = 0; i < 32; ++i) { lv[i] = __expf(lv[i] - m); ssum += lv[i]; }
      const float qs = SCALE_Q / ssum;
      uint_t* hw = (uint_t*)xs;
#pragma unroll
      for (int i = 0; i < 32; i += 2)
        hw[swzA(n2, hq * 32 + i) >> 1] = f2bf2(lv[i] * qs, lv[i + 1] * qs);
    }
    __syncthreads();
    // ---- out_att: oacc[nt] = qhat^T * ctx (per head K=32)
    f32x4 oacc[4];
#pragma unroll
    for (int nt = 0; nt < 4; ++nt) oacc[nt] = fzero;
#pragma unroll
    for (int hi = 0; hi < 2; ++hi) {
      const int h2 = ng * 2 + hi;
      short8 af = ldfragA(xs, mg * 16 + l15, h2 * 32 + l4 * 8, mg & 1);
#pragma unroll
      for (int et = 0; et < 2; ++et) {
        const int nt = hi * 2 + et;
        oacc[nt] = MFMA(af, cfr[nt], oacc[nt]);
      }
    }
    // ---- write yT [n][hid] via lane-pair shuffle (bf16 pairs along hid)
    {
      uint_t* yw = (uint_t*)yT;
#pragma unroll
      for (int nt = 0; nt < 4; ++nt) {
        const int hid = ng * 64 + nt * 16 + l15;
        const int hb = hid & ~1;
        const int nq = mg * 16 + l4 * 4;
        f32x4 v = oacc[nt];
        float o0 = __shfl_xor(v.x, 1), o1 = __shfl_xor(v.y, 1);
        float o2 = __shfl_xor(v.z, 1), o3 = __shfl_xor(v.w, 1);
        if ((lane & 1) == 0) {
          yw[swzA(nq, hb) >> 1] = f2bf2(v.x, o0);
          yw[swzA(nq + 1, hb) >> 1] = f2bf2(v.y, o1);
        } else {
          yw[swzA(nq + 2, hb) >> 1] = f2bf2(o2, v.z);
          yw[swzA(nq + 3, hb) >> 1] = f2bf2(o3, v.w);
        }
      }
    }
    __syncthreads();
    // ---- final GEMM: 64n x 128outc, K=128
    f32x4 facc[4];
#pragma unroll
    for (int nt = 0; nt < 4; ++nt) facc[nt] = fzero;
#pragma unroll
    for (int kk = 0; kk < 4; ++kk) {
      short8 wof[4];
#pragma unroll
      for (int nt = 0; nt < 4; ++nt)
        wof[nt] = *(const short8*)&wout_pk[((kk * 8 + ng * 4 + nt) * 64 + lane) * 8];
      short8 af = ldfragA(yT, mg * 16 + l15, kk * 32 + l4 * 8, mg & 1);
#pragma unroll
      for (int nt = 0; nt < 4; ++nt)
        facc[nt] = MFMA(af, wof[nt], facc[nt]);
    }
    // ---- bias + sum of squares
    float sq[4] = {0.f, 0.f, 0.f, 0.f};
#pragma unroll
    for (int nt = 0; nt < 4; ++nt) {
      const int outc = ng * 64 + nt * 16 + l15;
      const float bb = bias_l[outc];
      facc[nt].x += bb; facc[nt].y += bb;
      facc[nt].z += bb; facc[nt].w += bb;
      sq[0] += facc[nt].x * facc[nt].x;
      sq[1] += facc[nt].y * facc[nt].y;
      sq[2] += facc[nt].z * facc[nt].z;
      sq[3] += facc[nt].w * facc[nt].w;
    }
#pragma unroll
    for (int r = 0; r < 4; ++r) {
      sq[r] += __shfl_xor(sq[r], 1);
      sq[r] += __shfl_xor(sq[r], 2);
      sq[r] += __shfl_xor(sq[r], 4);
      sq[r] += __shfl_xor(sq[r], 8);
    }
    if (l15 == 0) {
#pragma unroll
      for (int r = 0; r < 4; ++r)
        atomicAdd(&nrm[mg * 16 + l4 * 4 + r], sq[r]);
    }
    __syncthreads();
    // ---- normalize + nontemporal store
    {
      const int nq = mg * 16 + l4 * 4;
      const float inv0 = RMS_K / fmaxf(sqrtf(nrm[nq + 0]), 1e-12f);
      const float inv1 = RMS_K / fmaxf(sqrtf(nrm[nq + 1]), 1e-12f);
      const float inv2 = RMS_K / fmaxf(sqrtf(nrm[nq + 2]), 1e-12f);
      const float inv3 = RMS_K / fmaxf(sqrtf(nrm[nq + 3]), 1e-12f);
#pragma unroll
      for (int nt = 0; nt < 4; ++nt) {
        const int outc = ng * 64 + nt * 16 + l15;
        const float gg = g_l[outc];
        f32x4 o;
        o.x = facc[nt].x * inv0 * gg;
        o.y = facc[nt].y * inv1 * gg;
        o.z = facc[nt].z * inv2 * gg;
        o.w = facc[nt].w * inv3 * gg;
        __builtin_nontemporal_store(o,
            (f32x4*)&out[(size_t)(b * 128 + outc) * NSEQ + blk * 256 + s * 64 + nq]);
      }
    }
  }
}

extern "C" void kernel_launch(void* const* d_in, const int* in_sizes, int n_in,
                              void* d_out, int out_size, void* d_ws, size_t ws_size,
                              hipStream_t stream) {
  const float* x = (const float*)d_in[0];
  const float* w_qkv = (const float*)d_in[1];
  const float* w_out = (const float*)d_in[2];
  const float* b_out = (const float*)d_in[3];
  const float* g = (const float*)d_in[4];
  float* out = (float*)d_out;

  float* ctx_acc = (float*)d_ws;                     // 32768 f32
  float* S_glob = ctx_acc + 32768;                   // 1024 f32
  ushort_t* wkv_pk = (ushort_t*)(S_glob + 1024);     // 32768 ush
  ushort_t* wq_pk = wkv_pk + 32768;                  // 16384 ush
  ushort_t* wout_pk = wq_pk + 16384;                 // 16384 ush
  ushort_t* ctx_pk = wout_pk + 16384;                // 32768 ush

  hipMemsetAsync(d_ws, 0, (32768 + 1024) * sizeof(float), stream);
  hipLaunchKernelGGL(kP, dim3(256), dim3(256), 0, stream, w_qkv, w_out, wkv_pk, wq_pk, wout_pk);
  hipLaunchKernelGGL(kA, dim3(64, 8), dim3(512), 0, stream, x, wkv_pk, ctx_acc, S_glob);
  hipLaunchKernelGGL(kB, dim3(32), dim3(256), 0, stream, ctx_acc, S_glob, ctx_pk);
  hipLaunchKernelGGL(kC, dim3(64, 8), dim3(512), 0, stream, x, wq_pk, wout_pk, ctx_pk, b_out, g, out);
}